// Round 3
// baseline (1166.602 us; speedup 1.0000x reference)
//
#include <hip/hip_runtime.h>
#include <math.h>

// Softmax splatting (softsplat, soft mode), fp32. B=4, C=16, H=512, W=960.
//
// v4: exact per-pixel CSR gather — every lane does useful work.
//   Theory from r2 counters: v3's broadcast-serial scan spent ~190us of
//   wave64 issue with <=4/64 useful lanes (VALUBusy 44% of 428us). Here each
//   target pixel owns an exact entry segment {src_p, w*exp(metric)}, and the
//   splat kernel is a per-lane serial loop of mean 4 entries, each one 64B
//   row gather + 17 FMAs at full lane utilization. No CAP (exact), no LDS
//   atomics, no broadcast loop.
//   Pipeline: memset | count (4 atomics/src) | alloc (block scan, 1 cursor
//   atomic/block) | fill (atomic post-increment, 8B entries) | 4x [prep
//   (channels-last 64B rows, per-batch 31.5MB buffer) + splat].
//   Workspace 111.1 MB (< 173 MB proven in r2). Denominator trick:
//   entry weight w' = w*m, inT holds PLAIN in -> num_c = sum w'*inT[c],
//   den = sum w'. No metric/exp needed in splat.
// Fallback: original verified 877us pair if workspace too small.

#define BB 4
#define CC 16
#define HH 512
#define WW 960
#define HWP (HH * WW)                 // 491520
#define NPIX (BB * HWP)               // 1966080
#define NENT (4 * NPIX)               // 7864320 (exact upper bound)
#define EPSF 1e-7f

// ---------------- v4 workspace layout ----------------
#define WS_CNT_OFF ((size_t)0)                         // u32[NPIX]   7,864,320
#define WS_CUR_OFF ((size_t)7864320)                   // u32 cursor
#define WS_OFF_OFF ((size_t)8388608)                   // u32[NPIX]   7,864,320
#define WS_INT_OFF ((size_t)16777216)                  // f32[HWP*16] 31,457,280 (one batch)
#define WS_ENT_OFF ((size_t)(16777216 + 31457280))     // uint2[NENT] 62,914,560
#define WS_NEED4   (WS_ENT_OFF + (size_t)NENT * 8)     // 111,149,056

// ---------------- fallback constants ----------------
#define TSX 32
#define TSY 16
#define TNX (WW / TSX)
#define TNY (HH / TSY)
#define TPB (TNX * TNY)
#define NTILE (BB * TPB)
#define CAP 1536

// ================= v4 path =================

__launch_bounds__(256)
__global__ void csr_count(const float* __restrict__ flow,
                          unsigned int* __restrict__ cnt)
{
    int b = blockIdx.z;
    int x = blockIdx.x * 32 + (threadIdx.x & 31);
    int y = blockIdx.y * 8  + (threadIdx.x >> 5);
    int p = y * WW + x;

    float dx = flow[(size_t)(b * 2 + 0) * HWP + p];
    float dy = flow[(size_t)(b * 2 + 1) * HWP + p];
    int x0 = (int)floorf((float)x + dx);
    int y0 = (int)floorf((float)y + dy);

    unsigned int* cb = cnt + (size_t)b * HWP;
#pragma unroll
    for (int k = 0; k < 4; ++k) {
        int xi = x0 + (k & 1), yi = y0 + (k >> 1);
        if (xi >= 0 && xi < WW && yi >= 0 && yi < HH)
            atomicAdd(&cb[yi * WW + xi], 1u);
    }
}

// Block scan: 480 blocks x 256 threads x 16 items = NPIX. One global-cursor
// atomic per block; off[i] = exact exclusive segment start.
__launch_bounds__(256)
__global__ void csr_alloc(const unsigned int* __restrict__ cnt,
                          unsigned int* __restrict__ off,
                          unsigned int* __restrict__ cursor)
{
    __shared__ unsigned int s[257];
    int t = threadIdx.x;
    size_t base = (size_t)blockIdx.x * 4096 + (size_t)t * 16;

    uint4 q0 = *(const uint4*)(cnt + base);
    uint4 q1 = *(const uint4*)(cnt + base + 4);
    uint4 q2 = *(const uint4*)(cnt + base + 8);
    uint4 q3 = *(const uint4*)(cnt + base + 12);

    unsigned int tsum = q0.x+q0.y+q0.z+q0.w + q1.x+q1.y+q1.z+q1.w
                      + q2.x+q2.y+q2.z+q2.w + q3.x+q3.y+q3.z+q3.w;
    s[t] = tsum;
    __syncthreads();
    for (int st = 1; st < 256; st <<= 1) {          // Hillis-Steele inclusive
        unsigned int v = (t >= st) ? s[t - st] : 0u;
        __syncthreads();
        s[t] += v;
        __syncthreads();
    }
    if (t == 255) s[256] = atomicAdd(cursor, s[255]);
    __syncthreads();

    unsigned int run = s[256] + s[t] - tsum;        // exclusive base for item 0
    uint4 o;
    o.x = run; run += q0.x;  o.y = run; run += q0.y;
    o.z = run; run += q0.z;  o.w = run; run += q0.w;
    *(uint4*)(off + base) = o;
    o.x = run; run += q1.x;  o.y = run; run += q1.y;
    o.z = run; run += q1.z;  o.w = run; run += q1.w;
    *(uint4*)(off + base + 4) = o;
    o.x = run; run += q2.x;  o.y = run; run += q2.y;
    o.z = run; run += q2.z;  o.w = run; run += q2.w;
    *(uint4*)(off + base + 8) = o;
    o.x = run; run += q3.x;  o.y = run; run += q3.y;
    o.z = run; run += q3.z;  o.w = run; run += q3.w;
    *(uint4*)(off + base + 12) = o;
}

__launch_bounds__(256)
__global__ void csr_fill(const float* __restrict__ flow,
                         const float* __restrict__ metric,
                         unsigned int* __restrict__ off,
                         uint2* __restrict__ ent)
{
    int b = blockIdx.z;
    int x = blockIdx.x * 32 + (threadIdx.x & 31);
    int y = blockIdx.y * 8  + (threadIdx.x >> 5);
    int p = y * WW + x;

    float dx = flow[(size_t)(b * 2 + 0) * HWP + p];
    float dy = flow[(size_t)(b * 2 + 1) * HWP + p];
    float m  = expf(metric[(size_t)b * HWP + p]);

    float fx = (float)x + dx, fy = (float)y + dy;
    float x0f = floorf(fx),   y0f = floorf(fy);
    int   x0 = (int)x0f,      y0 = (int)y0f;
    float wx1 = fx - x0f,     wy1 = fy - y0f;
    float wxa[2] = { 1.0f - wx1, wx1 };
    float wya[2] = { 1.0f - wy1, wy1 };

    unsigned int* ob = off + (size_t)b * HWP;
#pragma unroll
    for (int k = 0; k < 4; ++k) {                   // k constant -> wxa[k&1] static
        int xi = x0 + (k & 1), yi = y0 + (k >> 1);
        if (xi >= 0 && xi < WW && yi >= 0 && yi < HH) {
            unsigned int pos = atomicAdd(&ob[yi * WW + xi], 1u);
            ent[pos] = make_uint2((unsigned int)p,
                                  __float_as_uint(wxa[k & 1] * wya[k >> 1] * m));
        }
    }
    // after this kernel: off[pix] == segment END; start = end - cnt[pix]
}

__launch_bounds__(256)
__global__ void csr_prep(const float* __restrict__ in,
                         float4* __restrict__ inT, int b)
{
    int x = blockIdx.x * 32 + (threadIdx.x & 31);
    int y = blockIdx.y * 8  + (threadIdx.x >> 5);
    int p = y * WW + x;

    const float* ib = in + (size_t)b * CC * HWP + p;
    float4* o = inT + (size_t)p * 4;
#pragma unroll
    for (int k = 0; k < 4; ++k) {
        float4 r;
        r.x = ib[(size_t)(4 * k + 0) * HWP];
        r.y = ib[(size_t)(4 * k + 1) * HWP];
        r.z = ib[(size_t)(4 * k + 2) * HWP];
        r.w = ib[(size_t)(4 * k + 3) * HWP];
        o[k] = r;
    }
}

__launch_bounds__(256)
__global__ void csr_splat(const float4* __restrict__ inT,
                          const unsigned int* __restrict__ cnt,
                          const unsigned int* __restrict__ off,
                          const uint2* __restrict__ ent,
                          float* __restrict__ out, int b)
{
    int x = blockIdx.x * 32 + (threadIdx.x & 31);
    int y = blockIdx.y * 8  + (threadIdx.x >> 5);
    int p = y * WW + x;
    size_t gi = (size_t)b * HWP + p;

    unsigned int end = off[gi];
    unsigned int i   = end - cnt[gi];

    float4 A = make_float4(0.f,0.f,0.f,0.f), B = A, C = A, D = A;
    float  aw = 0.f;

    #define ACC1(wK, rK)                                                       \
        { float4 t0 = rK[0], t1 = rK[1], t2 = rK[2], t3 = rK[3];               \
          A.x += wK*t0.x; A.y += wK*t0.y; A.z += wK*t0.z; A.w += wK*t0.w;      \
          B.x += wK*t1.x; B.y += wK*t1.y; B.z += wK*t1.z; B.w += wK*t1.w;      \
          C.x += wK*t2.x; C.y += wK*t2.y; C.z += wK*t2.z; C.w += wK*t2.w;      \
          D.x += wK*t3.x; D.y += wK*t3.y; D.z += wK*t3.z; D.w += wK*t3.w;      \
          aw  += wK; }

    // 2-way unroll: two independent entry->row miss chains in flight
    for (; i + 2 <= end; i += 2) {
        uint2 E0 = ent[i], E1 = ent[i + 1];
        const float4* r0 = inT + (size_t)E0.x * 4;
        const float4* r1 = inT + (size_t)E1.x * 4;
        float w0 = __uint_as_float(E0.y);
        float w1 = __uint_as_float(E1.y);
        ACC1(w0, r0)
        ACC1(w1, r1)
    }
    if (i < end) {
        uint2 E0 = ent[i];
        const float4* r0 = inT + (size_t)E0.x * 4;
        float w0 = __uint_as_float(E0.y);
        ACC1(w0, r0)
    }
    #undef ACC1

    float inv = 1.0f / (aw + EPSF);
    float* ob = out + (size_t)b * CC * HWP + p;
    ob[(size_t) 0 * HWP] = A.x * inv;  ob[(size_t) 1 * HWP] = A.y * inv;
    ob[(size_t) 2 * HWP] = A.z * inv;  ob[(size_t) 3 * HWP] = A.w * inv;
    ob[(size_t) 4 * HWP] = B.x * inv;  ob[(size_t) 5 * HWP] = B.y * inv;
    ob[(size_t) 6 * HWP] = B.z * inv;  ob[(size_t) 7 * HWP] = B.w * inv;
    ob[(size_t) 8 * HWP] = C.x * inv;  ob[(size_t) 9 * HWP] = C.y * inv;
    ob[(size_t)10 * HWP] = C.z * inv;  ob[(size_t)11 * HWP] = C.w * inv;
    ob[(size_t)12 * HWP] = D.x * inv;  ob[(size_t)13 * HWP] = D.y * inv;
    ob[(size_t)14 * HWP] = D.z * inv;  ob[(size_t)15 * HWP] = D.w * inv;
}

// ================= fallback (original verified 877us) path =================

__launch_bounds__(256)
__global__ void bin_kernel(const float* __restrict__ flow,
                           unsigned int* __restrict__ counts,
                           unsigned int* __restrict__ bins)
{
    __shared__ unsigned int lcnt[TPB];

    int b  = blockIdx.z;
    int x  = blockIdx.x * 32 + (threadIdx.x & 31);
    int y  = blockIdx.y * 8  + (threadIdx.x >> 5);
    int p  = y * WW + x;

    for (int i = threadIdx.x; i < TPB; i += 256) lcnt[i] = 0;
    __syncthreads();

    float dx = flow[(size_t)(b * 2 + 0) * HWP + p];
    float dy = flow[(size_t)(b * 2 + 1) * HWP + p];
    int x0 = (int)floorf((float)x + dx);
    int y0 = (int)floorf((float)y + dy);

    int txA = x0 >> 5, txB = (x0 + 1) >> 5;
    int tyA = y0 >> 4, tyB = (y0 + 1) >> 4;

    int          tA[4];
    unsigned int rA[4];
    int cnt = 0;

    #define TRYINS(tx_, ty_)                                                   \
        if ((tx_) >= 0 && (tx_) < TNX && (ty_) >= 0 && (ty_) < TNY) {          \
            int t_ = (ty_) * TNX + (tx_);                                      \
            rA[cnt] = atomicAdd(&lcnt[t_], 1u);                                \
            tA[cnt] = t_;                                                      \
            ++cnt;                                                             \
        }

    TRYINS(txA, tyA);
    if (txB != txA) TRYINS(txB, tyA);
    if (tyB != tyA) {
        TRYINS(txA, tyB);
        if (txB != txA) TRYINS(txB, tyB);
    }
    #undef TRYINS

    __syncthreads();

    for (int i = threadIdx.x; i < TPB; i += 256) {
        unsigned int c = lcnt[i];
        if (c) lcnt[i] = atomicAdd(&counts[b * TPB + i], c);
    }
    __syncthreads();

    unsigned int e = ((unsigned int)y << 10) | (unsigned int)x;
    for (int k = 0; k < cnt; ++k) {
        int t_ = tA[k];
        unsigned int pos = lcnt[t_] + rA[k];
        if (pos < CAP)
            bins[((size_t)(b * TPB) + t_) * CAP + pos] = e;
    }
}

__launch_bounds__(256)
__global__ void tile_kernel(const float* __restrict__ in,
                            const float* __restrict__ flow,
                            const float* __restrict__ metric,
                            const unsigned int* __restrict__ counts,
                            const unsigned int* __restrict__ bins,
                            float* __restrict__ out)
{
    __shared__ float acc[TSX * TSY * 17];

    int tile = blockIdx.x;
    int b  = tile / TPB;
    int t  = tile - b * TPB;
    int ty = t / TNX;
    int tx = t - ty * TNX;
    int tid = threadIdx.x;

    for (int i = tid; i < TSX * TSY * 17; i += 256) acc[i] = 0.0f;
    __syncthreads();

    unsigned int n = counts[tile];
    if (n > CAP) n = CAP;

    for (unsigned int base = 0; base < n; base += 256) {
        unsigned int i = base + tid;
        if (i < n) {
            unsigned int e = bins[(size_t)tile * CAP + i];
            int x = (int)(e & 1023u);
            int y = (int)(e >> 10);
            int p = y * WW + x;

            float dx = flow[(size_t)(b * 2 + 0) * HWP + p];
            float dy = flow[(size_t)(b * 2 + 1) * HWP + p];
            float m  = expf(metric[(size_t)b * HWP + p]);

            float fx = (float)x + dx;
            float fy = (float)y + dy;
            float x0f = floorf(fx), y0f = floorf(fy);
            int   x0  = (int)x0f,   y0  = (int)y0f;
            float wx1 = fx - x0f,   wy1 = fy - y0f;
            float wx0 = 1.0f - wx1, wy0 = 1.0f - wy1;

            float v[CC];
            const float* inp = in + (size_t)b * CC * HWP + p;
#pragma unroll
            for (int c = 0; c < CC; ++c) v[c] = inp[(size_t)c * HWP] * m;

            const int   xs[4] = { x0,        x0 + 1,    x0,        x0 + 1    };
            const int   ys[4] = { y0,        y0,        y0 + 1,    y0 + 1    };
            const float ws[4] = { wx0 * wy0, wx1 * wy0, wx0 * wy1, wx1 * wy1 };

#pragma unroll
            for (int k = 0; k < 4; ++k) {
                int xi = xs[k], yi = ys[k];
                if ((xi >> 5) == tx && (yi >> 4) == ty) {
                    float wgt = ws[k];
                    int q = ((yi & 15) * TSX + (xi & 31)) * 17;
#pragma unroll
                    for (int c = 0; c < CC; ++c)
                        atomicAdd(&acc[q + c], v[c] * wgt);
                    atomicAdd(&acc[q + CC], m * wgt);
                }
            }
        }
    }
    __syncthreads();

    for (int q = tid; q < TSX * TSY; q += 256) {
        int ly = q >> 5, lx = q & 31;
        int gp = (ty * TSY + ly) * WW + tx * TSX + lx;
        float inv = 1.0f / (acc[q * 17 + CC] + EPSF);
        float* op = out + (size_t)b * CC * HWP + gp;
#pragma unroll
        for (int c = 0; c < CC; ++c)
            op[(size_t)c * HWP] = acc[q * 17 + c] * inv;
    }
}

// ================= launch =================

extern "C" void kernel_launch(void* const* d_in, const int* in_sizes, int n_in,
                              void* d_out, int out_size, void* d_ws, size_t ws_size,
                              hipStream_t stream) {
    const float* in     = (const float*)d_in[0];
    const float* flow   = (const float*)d_in[1];
    const float* metric = (const float*)d_in[2];
    float* out = (float*)d_out;

    if (ws_size >= WS_NEED4) {
        unsigned int* cnt    = (unsigned int*)((char*)d_ws + WS_CNT_OFF);
        unsigned int* cursor = (unsigned int*)((char*)d_ws + WS_CUR_OFF);
        unsigned int* off    = (unsigned int*)((char*)d_ws + WS_OFF_OFF);
        float4*       inT    = (float4*)((char*)d_ws + WS_INT_OFF);
        uint2*        ent    = (uint2*)((char*)d_ws + WS_ENT_OFF);

        // zero cnt + cursor in one memset
        hipMemsetAsync(d_ws, 0, WS_CUR_OFF + 4, stream);

        dim3 g2(WW / 32, HH / 8, BB);        // (30, 64, 4)
        csr_count<<<g2, dim3(256), 0, stream>>>(flow, cnt);
        csr_alloc<<<dim3(NPIX / 4096), dim3(256), 0, stream>>>(cnt, off, cursor);
        csr_fill <<<g2, dim3(256), 0, stream>>>(flow, metric, off, ent);

        dim3 g1(WW / 32, HH / 8);            // (30, 64) one batch
        for (int b = 0; b < BB; ++b) {
            csr_prep <<<g1, dim3(256), 0, stream>>>(in, inT, b);
            csr_splat<<<g1, dim3(256), 0, stream>>>(inT, cnt, off, ent, out, b);
        }
    } else {
        // fallback: original verified path (~877 us)
        unsigned int* counts = (unsigned int*)d_ws;
        unsigned int* bins   = (unsigned int*)((char*)d_ws + 16384);

        hipMemsetAsync(counts, 0, NTILE * sizeof(unsigned int), stream);

        bin_kernel<<<dim3(WW / 32, HH / 8, BB), dim3(256), 0, stream>>>(flow, counts, bins);
        tile_kernel<<<dim3(NTILE), dim3(256), 0, stream>>>(in, flow, metric, counts, bins, out);
    }
}

// Round 4
// 479.114 us; speedup vs baseline: 2.4349x; 2.4349x over previous
//
#include <hip/hip_runtime.h>
#include <math.h>

// Softmax splatting (softsplat, soft mode), fp32. B=4, C=16, H=512, W=960.
//
// v5: strip-dense gather. Lessons encoded:
//   r0/r1: LDS atomic scatter = ~700us wall.       -> no LDS atomics.
//   r2: wave-serial readlane scan, <=4/64 lanes    -> lane-per-pixel dense scan.
//   r3: pixel-sorted CSR fill = 500MB of 64B-line  -> band-clustered bin writes
//       amplification on 8B scattered stores.         (runs, like proven prep3).
// Structure (per batch):
//   prep5 : fused channels-last transpose (plain in; m folded into entry
//           weights) + binning to 32x2 strips. Entry 16B =
//           {p | (cx+1)<<19, wx1, m*w_row0, m*w_row1}; row weights resolved
//           per strip at prep time. LDS count table + one global atomic per
//           (block,strip), contiguous runs (no write amplification).
//   splat5: one wave per strip, one lane per pixel. readfirstlane(strip)
//           makes count/entry/value-row loads wave-uniform (scalar-path
//           eligible). Each entry: 1 uniform 16B entry load + 1 uniform 64B
//           row load + ~10 VALU weight calc + 17 predicated FMAs, all lanes
//           useful. Zero atomics, zero LDS, zero barriers. Coalesced
//           writeback fused with normalization.
// Fallback: original verified 877us pair if workspace too small.

#define BB 4
#define CC 16
#define HH 512
#define WW 960
#define HWP (HH * WW)
#define EPSF 1e-7f

// ---------------- v5 constants ----------------
#define NSX 30                        // col strips (32 wide)
#define NSY 256                       // row strips (2 tall)
#define SPB (NSX * NSY)               // 7680 strips per batch
#define CAPS 192                      // mean ~99, 9-sigma headroom

// workspace: counts[4][SPB] | bins[SPB][CAPS] (per batch) | inT (per batch)
#define WS_BINS_OFF ((size_t)131072)
#define WS_INT_OFF  (WS_BINS_OFF + (size_t)SPB * CAPS * 16)   // 23,724,032
#define WS_NEED5    (WS_INT_OFF + (size_t)HWP * 64)           // 55,181,312

// ---------------- fallback constants ----------------
#define TSX 32
#define TSY 16
#define TNX (WW / TSX)
#define TNY (HH / TSY)
#define TPB (TNX * TNY)
#define NTILE (BB * TPB)
#define CAP 1536

// ================= v5 path =================

__launch_bounds__(256)
__global__ void prep5(const float* __restrict__ in,
                      const float* __restrict__ flow,
                      const float* __restrict__ metric,
                      unsigned int* __restrict__ counts,   // this batch's SPB
                      uint4* __restrict__ bins,
                      float4* __restrict__ inT, int b)
{
    __shared__ unsigned int lcnt[SPB];   // 30720 B

    int x = blockIdx.x * 32 + (threadIdx.x & 31);
    int y = blockIdx.y * 8  + (threadIdx.x >> 5);
    int p = y * WW + x;

    for (int i = threadIdx.x; i < SPB; i += 256) lcnt[i] = 0;
    __syncthreads();

    float dx = flow[(size_t)(b * 2 + 0) * HWP + p];
    float dy = flow[(size_t)(b * 2 + 1) * HWP + p];
    float m  = expf(metric[(size_t)b * HWP + p]);

    // channels-last transpose (plain values; m rides in entry weights)
    const float* ib = in + (size_t)b * CC * HWP + p;
    float4* o = inT + (size_t)p * 4;
#pragma unroll
    for (int k = 0; k < 4; ++k) {
        float4 r;
        r.x = ib[(size_t)(4 * k + 0) * HWP];
        r.y = ib[(size_t)(4 * k + 1) * HWP];
        r.z = ib[(size_t)(4 * k + 2) * HWP];
        r.w = ib[(size_t)(4 * k + 3) * HWP];
        o[k] = r;
    }

    float fx = (float)x + dx, fy = (float)y + dy;
    float x0f = floorf(fx),   y0f = floorf(fy);
    int   x0 = (int)x0f,      y0 = (int)y0f;
    float wx1 = fx - x0f,     wy1 = fy - y0f;
    float wy0m = (1.0f - wy1) * m, wy1m = wy1 * m;

    int sxA = x0 >> 5, sxB = (x0 + 1) >> 5;     // arithmetic shift: floor div
    int syA = y0 >> 1, syB = (y0 + 1) >> 1;
    bool dupX = (sxB != sxA);
    bool dupY = (syB != syA);                   // == (y0 odd, incl. negatives)

    // row weights: strip syA has rows {2syA, 2syA+1}; strip syB rows {y0+1, y0+2}
    float w0AB = dupY ? 0.0f  : wy0m;
    float w1AB = dupY ? wy0m  : wy1m;
    float w0CD = wy1m;                          // only used when dupY
    // w1CD = 0

    bool vA = (sxA >= 0 && sxA < NSX && syA >= 0 && syA < NSY);
    bool vB = dupX && (sxB >= 0 && sxB < NSX && syA >= 0 && syA < NSY);
    bool vC = dupY && (sxA >= 0 && sxA < NSX && syB >= 0 && syB < NSY);
    bool vD = dupX && dupY && (sxB >= 0 && sxB < NSX && syB >= 0 && syB < NSY);

    int tA = syA * NSX + sxA, tB = syA * NSX + sxB;
    int tC = syB * NSX + sxA, tD = syB * NSX + sxB;

    unsigned int rA = 0, rB = 0, rC = 0, rD = 0;
    if (vA) rA = atomicAdd(&lcnt[tA], 1u);
    if (vB) rB = atomicAdd(&lcnt[tB], 1u);
    if (vC) rC = atomicAdd(&lcnt[tC], 1u);
    if (vD) rD = atomicAdd(&lcnt[tD], 1u);

    __syncthreads();

    // one contiguous global run per nonempty strip; base replaces count
    for (int i = threadIdx.x; i < SPB; i += 256) {
        unsigned int c = lcnt[i];
        if (c) lcnt[i] = atomicAdd(&counts[i], c);
    }
    __syncthreads();

    unsigned int pkA = (unsigned int)p | ((unsigned int)((x0 - (sxA << 5)) + 1) << 19);
    unsigned int pkB = (unsigned int)p;         // cx = -1 -> (cx+1) = 0
    unsigned int uwx = __float_as_uint(wx1);

    if (vA) { unsigned int pos = lcnt[tA] + rA;
        if (pos < CAPS) bins[(size_t)tA * CAPS + pos] =
            make_uint4(pkA, uwx, __float_as_uint(w0AB), __float_as_uint(w1AB)); }
    if (vB) { unsigned int pos = lcnt[tB] + rB;
        if (pos < CAPS) bins[(size_t)tB * CAPS + pos] =
            make_uint4(pkB, uwx, __float_as_uint(w0AB), __float_as_uint(w1AB)); }
    if (vC) { unsigned int pos = lcnt[tC] + rC;
        if (pos < CAPS) bins[(size_t)tC * CAPS + pos] =
            make_uint4(pkA, uwx, __float_as_uint(w0CD), __float_as_uint(0.0f)); }
    if (vD) { unsigned int pos = lcnt[tD] + rD;
        if (pos < CAPS) bins[(size_t)tD * CAPS + pos] =
            make_uint4(pkB, uwx, __float_as_uint(w0CD), __float_as_uint(0.0f)); }
}

__launch_bounds__(256)
__global__ void splat5(const float4* __restrict__ inT,
                       const unsigned int* __restrict__ counts,
                       const uint4* __restrict__ bins,
                       float* __restrict__ out, int b)
{
    int wave = threadIdx.x >> 6;
    int lane = threadIdx.x & 63;
    int bx   = blockIdx.x;               // 0..29
    int sy   = blockIdx.y * 4 + wave;    // 0..255
    // force wave-uniform chain -> scalar-path loads for count/entry/row
    int s = __builtin_amdgcn_readfirstlane(sy * NSX + bx);

    unsigned int n = counts[s];
    if (n > CAPS) n = CAPS;
    const uint4* bs = bins + (size_t)s * CAPS;

    int lx = lane & 31;                  // owned col within strip
    int ly = lane >> 5;                  // owned row within strip (0/1)

    float4 A = make_float4(0.f,0.f,0.f,0.f), B = A, C = A, D = A;
    float  aw = 0.f;

#pragma unroll 2
    for (unsigned int j = 0; j < n; ++j) {
        uint4 e = bs[j];                                  // uniform 16B
        int   p   = (int)(e.x & 0x7FFFFu);
        int   cx  = (int)((e.x >> 19) & 63u) - 1;         // [-1,31]
        float wx1 = __uint_as_float(e.y);
        float wrm = __uint_as_float(ly ? e.w : e.z);      // m*w for my row
        float wx  = (lx == cx) ? (1.0f - wx1)
                  : ((lx == cx + 1) ? wx1 : 0.0f);
        float w   = wx * wrm;                             // 0 for non-hit lanes

        const float4* r = inT + (size_t)p * 4;            // uniform 64B row
        float4 t0 = r[0], t1 = r[1], t2 = r[2], t3 = r[3];
        A.x += w * t0.x; A.y += w * t0.y; A.z += w * t0.z; A.w += w * t0.w;
        B.x += w * t1.x; B.y += w * t1.y; B.z += w * t1.z; B.w += w * t1.w;
        C.x += w * t2.x; C.y += w * t2.y; C.z += w * t2.z; C.w += w * t2.w;
        D.x += w * t3.x; D.y += w * t3.y; D.z += w * t3.z; D.w += w * t3.w;
        aw  += w;
    }

    // coalesced writeback + fused normalization: one pixel per lane
    float inv = 1.0f / (aw + EPSF);
    int xg = bx * 32 + lx;
    int yg = sy * 2 + ly;
    float* ob = out + (size_t)b * CC * HWP + (size_t)yg * WW + xg;
    ob[(size_t) 0 * HWP] = A.x * inv;  ob[(size_t) 1 * HWP] = A.y * inv;
    ob[(size_t) 2 * HWP] = A.z * inv;  ob[(size_t) 3 * HWP] = A.w * inv;
    ob[(size_t) 4 * HWP] = B.x * inv;  ob[(size_t) 5 * HWP] = B.y * inv;
    ob[(size_t) 6 * HWP] = B.z * inv;  ob[(size_t) 7 * HWP] = B.w * inv;
    ob[(size_t) 8 * HWP] = C.x * inv;  ob[(size_t) 9 * HWP] = C.y * inv;
    ob[(size_t)10 * HWP] = C.z * inv;  ob[(size_t)11 * HWP] = C.w * inv;
    ob[(size_t)12 * HWP] = D.x * inv;  ob[(size_t)13 * HWP] = D.y * inv;
    ob[(size_t)14 * HWP] = D.z * inv;  ob[(size_t)15 * HWP] = D.w * inv;
}

// ================= fallback (original verified 877us) path =================

__launch_bounds__(256)
__global__ void bin_kernel(const float* __restrict__ flow,
                           unsigned int* __restrict__ counts,
                           unsigned int* __restrict__ bins)
{
    __shared__ unsigned int lcnt[TPB];

    int b  = blockIdx.z;
    int x  = blockIdx.x * 32 + (threadIdx.x & 31);
    int y  = blockIdx.y * 8  + (threadIdx.x >> 5);
    int p  = y * WW + x;

    for (int i = threadIdx.x; i < TPB; i += 256) lcnt[i] = 0;
    __syncthreads();

    float dx = flow[(size_t)(b * 2 + 0) * HWP + p];
    float dy = flow[(size_t)(b * 2 + 1) * HWP + p];
    int x0 = (int)floorf((float)x + dx);
    int y0 = (int)floorf((float)y + dy);

    int txA = x0 >> 5, txB = (x0 + 1) >> 5;
    int tyA = y0 >> 4, tyB = (y0 + 1) >> 4;

    int          tA[4];
    unsigned int rA[4];
    int cnt = 0;

    #define TRYINS(tx_, ty_)                                                   \
        if ((tx_) >= 0 && (tx_) < TNX && (ty_) >= 0 && (ty_) < TNY) {          \
            int t_ = (ty_) * TNX + (tx_);                                      \
            rA[cnt] = atomicAdd(&lcnt[t_], 1u);                                \
            tA[cnt] = t_;                                                      \
            ++cnt;                                                             \
        }

    TRYINS(txA, tyA);
    if (txB != txA) TRYINS(txB, tyA);
    if (tyB != tyA) {
        TRYINS(txA, tyB);
        if (txB != txA) TRYINS(txB, tyB);
    }
    #undef TRYINS

    __syncthreads();

    for (int i = threadIdx.x; i < TPB; i += 256) {
        unsigned int c = lcnt[i];
        if (c) lcnt[i] = atomicAdd(&counts[b * TPB + i], c);
    }
    __syncthreads();

    unsigned int e = ((unsigned int)y << 10) | (unsigned int)x;
    for (int k = 0; k < cnt; ++k) {
        int t_ = tA[k];
        unsigned int pos = lcnt[t_] + rA[k];
        if (pos < CAP)
            bins[((size_t)(b * TPB) + t_) * CAP + pos] = e;
    }
}

__launch_bounds__(256)
__global__ void tile_kernel(const float* __restrict__ in,
                            const float* __restrict__ flow,
                            const float* __restrict__ metric,
                            const unsigned int* __restrict__ counts,
                            const unsigned int* __restrict__ bins,
                            float* __restrict__ out)
{
    __shared__ float acc[TSX * TSY * 17];

    int tile = blockIdx.x;
    int b  = tile / TPB;
    int t  = tile - b * TPB;
    int ty = t / TNX;
    int tx = t - ty * TNX;
    int tid = threadIdx.x;

    for (int i = tid; i < TSX * TSY * 17; i += 256) acc[i] = 0.0f;
    __syncthreads();

    unsigned int n = counts[tile];
    if (n > CAP) n = CAP;

    for (unsigned int base = 0; base < n; base += 256) {
        unsigned int i = base + tid;
        if (i < n) {
            unsigned int e = bins[(size_t)tile * CAP + i];
            int x = (int)(e & 1023u);
            int y = (int)(e >> 10);
            int p = y * WW + x;

            float dx = flow[(size_t)(b * 2 + 0) * HWP + p];
            float dy = flow[(size_t)(b * 2 + 1) * HWP + p];
            float m  = expf(metric[(size_t)b * HWP + p]);

            float fx = (float)x + dx;
            float fy = (float)y + dy;
            float x0f = floorf(fx), y0f = floorf(fy);
            int   x0  = (int)x0f,   y0  = (int)y0f;
            float wx1 = fx - x0f,   wy1 = fy - y0f;
            float wx0 = 1.0f - wx1, wy0 = 1.0f - wy1;

            float v[CC];
            const float* inp = in + (size_t)b * CC * HWP + p;
#pragma unroll
            for (int c = 0; c < CC; ++c) v[c] = inp[(size_t)c * HWP] * m;

            const int   xs[4] = { x0,        x0 + 1,    x0,        x0 + 1    };
            const int   ys[4] = { y0,        y0,        y0 + 1,    y0 + 1    };
            const float ws[4] = { wx0 * wy0, wx1 * wy0, wx0 * wy1, wx1 * wy1 };

#pragma unroll
            for (int k = 0; k < 4; ++k) {
                int xi = xs[k], yi = ys[k];
                if ((xi >> 5) == tx && (yi >> 4) == ty) {
                    float wgt = ws[k];
                    int q = ((yi & 15) * TSX + (xi & 31)) * 17;
#pragma unroll
                    for (int c = 0; c < CC; ++c)
                        atomicAdd(&acc[q + c], v[c] * wgt);
                    atomicAdd(&acc[q + CC], m * wgt);
                }
            }
        }
    }
    __syncthreads();

    for (int q = tid; q < TSX * TSY; q += 256) {
        int ly = q >> 5, lx = q & 31;
        int gp = (ty * TSY + ly) * WW + tx * TSX + lx;
        float inv = 1.0f / (acc[q * 17 + CC] + EPSF);
        float* op = out + (size_t)b * CC * HWP + gp;
#pragma unroll
        for (int c = 0; c < CC; ++c)
            op[(size_t)c * HWP] = acc[q * 17 + c] * inv;
    }
}

// ================= launch =================

extern "C" void kernel_launch(void* const* d_in, const int* in_sizes, int n_in,
                              void* d_out, int out_size, void* d_ws, size_t ws_size,
                              hipStream_t stream) {
    const float* in     = (const float*)d_in[0];
    const float* flow   = (const float*)d_in[1];
    const float* metric = (const float*)d_in[2];
    float* out = (float*)d_out;

    if (ws_size >= WS_NEED5) {
        unsigned int* counts = (unsigned int*)d_ws;      // [BB][SPB]
        uint4*        bins   = (uint4*)((char*)d_ws + WS_BINS_OFF);
        float4*       inT    = (float4*)((char*)d_ws + WS_INT_OFF);

        hipMemsetAsync(counts, 0, (size_t)BB * SPB * 4, stream);

        for (int b = 0; b < BB; ++b) {
            prep5 <<<dim3(NSX, 64), dim3(256), 0, stream>>>(
                in, flow, metric, counts + (size_t)b * SPB, bins, inT, b);
            splat5<<<dim3(NSX, 64), dim3(256), 0, stream>>>(
                inT, counts + (size_t)b * SPB, bins, out, b);
        }
    } else {
        // fallback: original verified path (~877 us)
        unsigned int* counts = (unsigned int*)d_ws;
        unsigned int* bins   = (unsigned int*)((char*)d_ws + 16384);

        hipMemsetAsync(counts, 0, NTILE * sizeof(unsigned int), stream);

        bin_kernel<<<dim3(WW / 32, HH / 8, BB), dim3(256), 0, stream>>>(flow, counts, bins);
        tile_kernel<<<dim3(NTILE), dim3(256), 0, stream>>>(in, flow, metric, counts, bins, out);
    }
}